// Round 1
// baseline (746.768 us; speedup 1.0000x reference)
//
#include <hip/hip_runtime.h>

#define D 128

// ---------------------------------------------------------------------------
// Kernel 1: Wh[n,:] = W (128x128) * h[n,:] + b       (f32 vector FMA)
// Each pair of threads handles one node; each thread computes 64 outputs.
// h row lives in 128 VGPRs (fully unrolled); W/bias are read with
// block-uniform indices -> compiler emits scalar loads (SGPR operand FMA).
// ---------------------------------------------------------------------------
__global__ __launch_bounds__(256) void wh_gemm_kernel(
    const float* __restrict__ h, const float* __restrict__ W,
    const float* __restrict__ bias, float* __restrict__ Wh, int N)
{
    int t = blockIdx.x * blockDim.x + threadIdx.x;
    int n = t >> 1;
    int half = t & 1;
    if (n >= N) return;

    float hreg[D];
    const float4* hv = reinterpret_cast<const float4*>(h + (size_t)n * D);
    float4* hr = reinterpret_cast<float4*>(hreg);
#pragma unroll
    for (int i = 0; i < D / 4; ++i) hr[i] = hv[i];

    const int dbase = half * 64;
    float4* out = reinterpret_cast<float4*>(Wh + (size_t)n * D + dbase);

    for (int dd = 0; dd < 64; dd += 4) {
        const int d0 = dbase + dd;
        float a0 = bias[d0 + 0];
        float a1 = bias[d0 + 1];
        float a2 = bias[d0 + 2];
        float a3 = bias[d0 + 3];
        const float* w = W + (size_t)d0 * D;   // rows d0..d0+3 of W
#pragma unroll
        for (int k = 0; k < D; ++k) {
            const float hk = hreg[k];
            a0 = fmaf(w[k],         hk, a0);
            a1 = fmaf(w[D + k],     hk, a1);
            a2 = fmaf(w[2 * D + k], hk, a2);
            a3 = fmaf(w[3 * D + k], hk, a3);
        }
        out[dd >> 2] = make_float4(a0, a1, a2, a3);
    }
}

// ---------------------------------------------------------------------------
// Kernel 2: scores[e] = dot(Wh[src[e],:], h[dst[e],:])
// 32 lanes per edge; lane i loads float4 #i of each 512B row (coalesced),
// dot4 in registers, 5-step shfl_xor butterfly within the 32-lane group.
// ---------------------------------------------------------------------------
__global__ __launch_bounds__(256) void edge_score_kernel(
    const float* __restrict__ Wh, const float* __restrict__ h,
    const int* __restrict__ src, const int* __restrict__ dst,
    float* __restrict__ out, int E)
{
    long long t = (long long)blockIdx.x * blockDim.x + threadIdx.x;
    int e = (int)(t >> 5);
    int lane = (int)(t & 31);
    if (e >= E) return;

    const int s = src[e];
    const int d = dst[e];

    const float4* a = reinterpret_cast<const float4*>(Wh + (size_t)s * D);
    const float4* b = reinterpret_cast<const float4*>(h  + (size_t)d * D);
    const float4 av = a[lane];
    const float4 bv = b[lane];

    float acc = av.x * bv.x + av.y * bv.y + av.z * bv.z + av.w * bv.w;
#pragma unroll
    for (int m = 16; m > 0; m >>= 1)
        acc += __shfl_xor(acc, m, 64);

    if (lane == 0) out[e] = acc;
}

extern "C" void kernel_launch(void* const* d_in, const int* in_sizes, int n_in,
                              void* d_out, int out_size, void* d_ws, size_t ws_size,
                              hipStream_t stream)
{
    const float* h   = (const float*)d_in[0];
    const int*   src = (const int*)  d_in[1];
    const int*   dst = (const int*)  d_in[2];
    const float* W   = (const float*)d_in[3];
    const float* b   = (const float*)d_in[4];
    float* out = (float*)d_out;

    const int N = in_sizes[0] / D;   // 100000
    const int E = in_sizes[1];       // 600000

    float* Wh = (float*)d_ws;        // N*D*4 = 51.2 MB scratch

    // GEMM: 2 threads per node
    {
        const int total = N * 2;
        const int blocks = (total + 255) / 256;
        wh_gemm_kernel<<<blocks, 256, 0, stream>>>(h, W, b, Wh, N);
    }
    // Edge scores: 32 threads per edge
    {
        const long long total = (long long)E * 32;
        const int blocks = (int)((total + 255) / 256);
        edge_score_kernel<<<blocks, 256, 0, stream>>>(Wh, h, src, dst, out, E);
    }
}

// Round 4
// 221.938 us; speedup vs baseline: 3.3648x; 3.3648x over previous
//
#include <hip/hip_runtime.h>
#include <hip/hip_bf16.h>

#define D 128

// ---- bf16 helpers (manual, RNE — matches HW convert for non-NaN) ----------
__device__ __forceinline__ unsigned int f2bf_bits(float f) {
    union { float f; unsigned int u; } c; c.f = f;
    return (c.u + 0x7fffu + ((c.u >> 16) & 1u)) >> 16;
}
__device__ __forceinline__ unsigned int pack2bf(float a, float b) {
    return f2bf_bits(a) | (f2bf_bits(b) << 16);
}
__device__ __forceinline__ float bf_lo(unsigned int u) {
    union { unsigned int u; float f; } c; c.u = u << 16; return c.f;
}
__device__ __forceinline__ float bf_hi(unsigned int u) {
    union { unsigned int u; float f; } c; c.u = u & 0xffff0000u; return c.f;
}

// ---------------------------------------------------------------------------
// Kernel 1: Wh = h @ W^T + b, output bf16; also converts h -> bf16.
// Block = 64 nodes x 4 waves. lane = node, wave = 32-column slice of W.
// W addresses are wave-uniform -> scalar s_load path; h row re-read as
// float4 per k-step (L1-resident: 32 KB/block).
// ---------------------------------------------------------------------------
__global__ __launch_bounds__(256) void wh_gemm_kernel(
    const float* __restrict__ h, const float* __restrict__ W,
    const float* __restrict__ bias, ushort* __restrict__ Wh_bf,
    ushort* __restrict__ h_bf, int N)
{
    const int lane = threadIdx.x & 63;
    const int wv   = __builtin_amdgcn_readfirstlane(threadIdx.x >> 6); // 0..3
    const int node = blockIdx.x * 64 + lane;
    if (node >= N) return;

    const float4* hv = reinterpret_cast<const float4*>(h + (size_t)node * D);
    const int d0 = wv * 32;   // wave-uniform column base

    float acc[32];
#pragma unroll
    for (int j = 0; j < 32; ++j) acc[j] = bias[d0 + j];   // uniform -> s_load

    for (int k = 0; k < D; k += 4) {
        const float4 hk = hv[k >> 2];          // vector load, L1-hot
#pragma unroll
        for (int j = 0; j < 32; ++j) {
            // uniform address -> scalar load, FMA with SGPR operand
            const float4 w = *reinterpret_cast<const float4*>(
                W + (size_t)(d0 + j) * D + k);
            float a = acc[j];
            a = fmaf(w.x, hk.x, a);
            a = fmaf(w.y, hk.y, a);
            a = fmaf(w.z, hk.z, a);
            a = fmaf(w.w, hk.w, a);
            acc[j] = a;
        }
    }

    // pack 32 results -> bf16, one contiguous 64B store region per lane
    {
        uint4 wds[4];
        unsigned int* wp = reinterpret_cast<unsigned int*>(wds);
#pragma unroll
        for (int i = 0; i < 16; ++i) wp[i] = pack2bf(acc[2 * i], acc[2 * i + 1]);
        uint4* dst = reinterpret_cast<uint4*>(Wh_bf + (size_t)node * D + d0);
#pragma unroll
        for (int i = 0; i < 4; ++i) dst[i] = wds[i];
    }

    // h -> bf16: wave wv converts its 32-element slice (cols d0..d0+31).
    // BUGFIX (round 3): must convert 8 float4s -> 4 uint4s (32 elements),
    // previous version only wrote 16, leaving poison in h_bf.
    {
        uint4 wds[4];
        unsigned int* wp = reinterpret_cast<unsigned int*>(wds);
#pragma unroll
        for (int i = 0; i < 8; ++i) {
            const float4 x = hv[(d0 >> 2) + i];
            wp[2 * i]     = pack2bf(x.x, x.y);
            wp[2 * i + 1] = pack2bf(x.z, x.w);
        }
        uint4* dst = reinterpret_cast<uint4*>(h_bf + (size_t)node * D + d0);
#pragma unroll
        for (int i = 0; i < 4; ++i) dst[i] = wds[i];
    }
}

// ---------------------------------------------------------------------------
// Kernel 2: scores[e] = dot(Wh_bf[src[e],:], h_bf[dst[e],:])
// 16 lanes per edge; lane i loads uint4 = 8 bf16 of each 256B row (coalesced),
// f32 accumulate, 4-step shfl_xor butterfly within the 16-lane group.
// ---------------------------------------------------------------------------
__global__ __launch_bounds__(256) void edge_score_kernel(
    const ushort* __restrict__ Wh_bf, const ushort* __restrict__ h_bf,
    const int* __restrict__ src, const int* __restrict__ dst,
    float* __restrict__ out, int E)
{
    const long long t = (long long)blockIdx.x * blockDim.x + threadIdx.x;
    const int e = (int)(t >> 4);
    const int l = (int)(t & 15);
    if (e >= E) return;

    const int s = src[e];
    const int d = dst[e];

    const uint4 av = reinterpret_cast<const uint4*>(Wh_bf + (size_t)s * D)[l];
    const uint4 bv = reinterpret_cast<const uint4*>(h_bf  + (size_t)d * D)[l];

    float acc = 0.f;
    acc = fmaf(bf_lo(av.x), bf_lo(bv.x), acc);
    acc = fmaf(bf_hi(av.x), bf_hi(bv.x), acc);
    acc = fmaf(bf_lo(av.y), bf_lo(bv.y), acc);
    acc = fmaf(bf_hi(av.y), bf_hi(bv.y), acc);
    acc = fmaf(bf_lo(av.z), bf_lo(bv.z), acc);
    acc = fmaf(bf_hi(av.z), bf_hi(bv.z), acc);
    acc = fmaf(bf_lo(av.w), bf_lo(bv.w), acc);
    acc = fmaf(bf_hi(av.w), bf_hi(bv.w), acc);

#pragma unroll
    for (int m = 8; m > 0; m >>= 1)
        acc += __shfl_xor(acc, m, 64);

    if (l == 0) out[e] = acc;
}

extern "C" void kernel_launch(void* const* d_in, const int* in_sizes, int n_in,
                              void* d_out, int out_size, void* d_ws, size_t ws_size,
                              hipStream_t stream)
{
    const float* h   = (const float*)d_in[0];
    const int*   src = (const int*)  d_in[1];
    const int*   dst = (const int*)  d_in[2];
    const float* W   = (const float*)d_in[3];
    const float* b   = (const float*)d_in[4];
    float* out = (float*)d_out;

    const int N = in_sizes[0] / D;   // 100000
    const int E = in_sizes[1];       // 600000

    ushort* Wh_bf = (ushort*)d_ws;                       // N*D*2 = 25.6 MB
    ushort* h_bf  = (ushort*)d_ws + (size_t)N * D;       // N*D*2 = 25.6 MB

    {
        const int blocks = (N + 63) / 64;                // 64 nodes per block
        wh_gemm_kernel<<<blocks, 256, 0, stream>>>(h, W, b, Wh_bf, h_bf, N);
    }
    {
        const long long total = (long long)E * 16;
        const int blocks = (int)((total + 255) / 256);
        edge_score_kernel<<<blocks, 256, 0, stream>>>(Wh_bf, h_bf, src, dst, out, E);
    }
}

// Round 5
// 150.985 us; speedup vs baseline: 4.9460x; 1.4699x over previous
//
#include <hip/hip_runtime.h>
#include <hip/hip_bf16.h>

#define D 128

typedef __attribute__((ext_vector_type(8))) short bf16x8;
typedef __attribute__((ext_vector_type(4))) float f32x4;

// ---- bf16 helpers (manual, RNE) -------------------------------------------
__device__ __forceinline__ unsigned int f2bf_bits(float f) {
    union { float f; unsigned int u; } c; c.f = f;
    return (c.u + 0x7fffu + ((c.u >> 16) & 1u)) >> 16;
}
__device__ __forceinline__ unsigned int pack2bf(float a, float b) {
    return f2bf_bits(a) | (f2bf_bits(b) << 16);
}
__device__ __forceinline__ float bf_lo(unsigned int u) {
    union { unsigned int u; float f; } c; c.u = u << 16; return c.f;
}
__device__ __forceinline__ float bf_hi(unsigned int u) {
    union { unsigned int u; float f; } c; c.u = u & 0xffff0000u; return c.f;
}

// ---------------------------------------------------------------------------
// Kernel 1 (MFMA): Wh_bf = bf16(h @ W^T + b); also emits h_bf.
// Block = 64 nodes, 4 waves; wave w computes nodes w*16..w*16+15 x all 128
// cols via 8 col-tiles of mfma_f32_16x16x32_bf16 (4 k-steps each).
// h-tile (16KB) and W (32KB) staged in LDS as bf16 with XOR swizzle
// (byte ^= (row&7)<<4) so 16-row column reads are bank-conflict-free.
// A/B frags use the same assumed k-order -> shared k-permutation cancels.
// C/D mapping (HW-verified): col = lane&15, row = (lane>>4)*4 + reg.
// ---------------------------------------------------------------------------
__global__ __launch_bounds__(256) void wh_mfma_kernel(
    const float* __restrict__ h, const float* __restrict__ W,
    const float* __restrict__ bias, ushort* __restrict__ Wh_bf,
    ushort* __restrict__ h_bf, int N)
{
    __shared__ alignas(16) unsigned char lds_h[64 * 256];   // [64][128] bf16, swizzled
    __shared__ alignas(16) unsigned char lds_w[128 * 256];  // [128][128] bf16, swizzled

    const int t = threadIdx.x;
    const int nodeBase = blockIdx.x * 64;

    // ---- stage h tile: 64 rows x 32 float4 segs; convert f32->bf16 --------
#pragma unroll
    for (int it = 0; it < 8; ++it) {
        const int idx = t + 256 * it;           // 0..2047
        const int row = idx >> 5;               // 0..63
        const int seg = idx & 31;               // float4 segment (4 f32)
        const int node = nodeBase + row;
        float4 x = make_float4(0.f, 0.f, 0.f, 0.f);
        if (node < N)
            x = reinterpret_cast<const float4*>(h)[(size_t)node * 32 + seg];
        const uint2 p = make_uint2(pack2bf(x.x, x.y), pack2bf(x.z, x.w));
        const int boff = (seg * 8) ^ ((row & 7) << 4);
        *reinterpret_cast<uint2*>(&lds_h[row * 256 + boff]) = p;
        if (node < N)   // linear global layout for the edge kernel
            *reinterpret_cast<uint2*>(h_bf + (size_t)node * D + seg * 4) = p;
    }
    // ---- stage W: 128 rows x 32 segs (64KB f32, L2-hot across blocks) ------
#pragma unroll
    for (int it = 0; it < 16; ++it) {
        const int idx = t + 256 * it;           // 0..4095
        const int row = idx >> 5;               // 0..127
        const int seg = idx & 31;
        const float4 x = reinterpret_cast<const float4*>(W)[idx];
        const uint2 p = make_uint2(pack2bf(x.x, x.y), pack2bf(x.z, x.w));
        const int boff = (seg * 8) ^ ((row & 7) << 4);
        *reinterpret_cast<uint2*>(&lds_w[row * 256 + boff]) = p;
    }
    __syncthreads();

    const int lane = t & 63;
    const int wv   = t >> 6;        // 0..3
    const int lr   = lane & 15;     // M/N index within tile
    const int g    = lane >> 4;     // k-group 0..3

    // A fragments: row = wv*16 + lr, 16B at k-offset kt*64 + g*16 (swizzled)
    bf16x8 afrag[4];
    {
        const int row = wv * 16 + lr;
#pragma unroll
        for (int kt = 0; kt < 4; ++kt) {
            const int boff = (kt * 64 + g * 16) ^ ((row & 7) << 4);
            afrag[kt] = *reinterpret_cast<const bf16x8*>(&lds_h[row * 256 + boff]);
        }
    }

#pragma unroll
    for (int ct = 0; ct < 8; ++ct) {
        const int wrow = ct * 16 + lr;          // W row == output col n
        const float bb = bias[wrow];
        f32x4 acc = {bb, bb, bb, bb};
#pragma unroll
        for (int kt = 0; kt < 4; ++kt) {
            const int boff = (kt * 64 + g * 16) ^ ((wrow & 7) << 4);
            const bf16x8 bfrag =
                *reinterpret_cast<const bf16x8*>(&lds_w[wrow * 256 + boff]);
            acc = __builtin_amdgcn_mfma_f32_16x16x32_bf16(afrag[kt], bfrag, acc, 0, 0, 0);
        }
        // store: lane holds col = wrow, rows m = g*4 + r within wave tile
        const int node0 = nodeBase + wv * 16 + g * 4;
#pragma unroll
        for (int r = 0; r < 4; ++r) {
            if (node0 + r < N)
                Wh_bf[(size_t)(node0 + r) * D + wrow] = (ushort)f2bf_bits(acc[r]);
        }
    }
}

// ---------------------------------------------------------------------------
// Kernel 2: scores[e] = dot(Wh_bf[src[e],:], h_bf[dst[e],:])
// 16 lanes per edge; lane i loads uint4 = 8 bf16 of each 256B row (coalesced),
// f32 accumulate, 4-step shfl_xor butterfly within the 16-lane group.
// ---------------------------------------------------------------------------
__global__ __launch_bounds__(256) void edge_score_kernel(
    const ushort* __restrict__ Wh_bf, const ushort* __restrict__ h_bf,
    const int* __restrict__ src, const int* __restrict__ dst,
    float* __restrict__ out, int E)
{
    const long long t = (long long)blockIdx.x * blockDim.x + threadIdx.x;
    const int e = (int)(t >> 4);
    const int l = (int)(t & 15);
    if (e >= E) return;

    const int s = src[e];
    const int d = dst[e];

    const uint4 av = reinterpret_cast<const uint4*>(Wh_bf + (size_t)s * D)[l];
    const uint4 bv = reinterpret_cast<const uint4*>(h_bf  + (size_t)d * D)[l];

    float acc = 0.f;
    acc = fmaf(bf_lo(av.x), bf_lo(bv.x), acc);
    acc = fmaf(bf_hi(av.x), bf_hi(bv.x), acc);
    acc = fmaf(bf_lo(av.y), bf_lo(bv.y), acc);
    acc = fmaf(bf_hi(av.y), bf_hi(bv.y), acc);
    acc = fmaf(bf_lo(av.z), bf_lo(bv.z), acc);
    acc = fmaf(bf_hi(av.z), bf_hi(bv.z), acc);
    acc = fmaf(bf_lo(av.w), bf_lo(bv.w), acc);
    acc = fmaf(bf_hi(av.w), bf_hi(bv.w), acc);

#pragma unroll
    for (int m = 8; m > 0; m >>= 1)
        acc += __shfl_xor(acc, m, 64);

    if (l == 0) out[e] = acc;
}

extern "C" void kernel_launch(void* const* d_in, const int* in_sizes, int n_in,
                              void* d_out, int out_size, void* d_ws, size_t ws_size,
                              hipStream_t stream)
{
    const float* h   = (const float*)d_in[0];
    const int*   src = (const int*)  d_in[1];
    const int*   dst = (const int*)  d_in[2];
    const float* W   = (const float*)d_in[3];
    const float* b   = (const float*)d_in[4];
    float* out = (float*)d_out;

    const int N = in_sizes[0] / D;   // 100000
    const int E = in_sizes[1];       // 600000

    ushort* Wh_bf = (ushort*)d_ws;                       // N*D*2 = 25.6 MB
    ushort* h_bf  = (ushort*)d_ws + (size_t)N * D;       // N*D*2 = 25.6 MB

    {
        const int blocks = (N + 63) / 64;                // 64 nodes per block
        wh_mfma_kernel<<<blocks, 256, 0, stream>>>(h, W, b, Wh_bf, h_bf, N);
    }
    {
        const long long total = (long long)E * 16;
        const int blocks = (int)((total + 255) / 256);
        edge_score_kernel<<<blocks, 256, 0, stream>>>(Wh_bf, h_bf, src, dst, out, E);
    }
}

// Round 6
// 148.396 us; speedup vs baseline: 5.0323x; 1.0174x over previous
//
#include <hip/hip_runtime.h>
#include <hip/hip_bf16.h>

#define D 128

typedef __attribute__((ext_vector_type(8))) short bf16x8;
typedef __attribute__((ext_vector_type(4))) float f32x4;

// ---- bf16 helpers ---------------------------------------------------------
__device__ __forceinline__ unsigned int f2bf_bits(float f) {
    union { float f; unsigned int u; } c; c.f = f;
    return (c.u + 0x7fffu + ((c.u >> 16) & 1u)) >> 16;
}
__device__ __forceinline__ unsigned int pack2bf(float a, float b) {
    // packed RNE convert; compiler lowers to v_cvt_pk_bf16_f32 when it can
    union { __hip_bfloat162 h; unsigned int u; } c;
    c.h = __float22bfloat162_rn(make_float2(a, b));
    return c.u;
}
__device__ __forceinline__ float bf_lo(unsigned int u) {
    union { unsigned int u; float f; } c; c.u = u << 16; return c.f;
}
__device__ __forceinline__ float bf_hi(unsigned int u) {
    union { unsigned int u; float f; } c; c.u = u & 0xffff0000u; return c.f;
}

// dot of 8 bf16 pairs (one uint4 per operand), f32 accumulate
__device__ __forceinline__ float dot8(uint4 a, uint4 b, float acc) {
    acc = fmaf(bf_lo(a.x), bf_lo(b.x), acc);
    acc = fmaf(bf_hi(a.x), bf_hi(b.x), acc);
    acc = fmaf(bf_lo(a.y), bf_lo(b.y), acc);
    acc = fmaf(bf_hi(a.y), bf_hi(b.y), acc);
    acc = fmaf(bf_lo(a.z), bf_lo(b.z), acc);
    acc = fmaf(bf_hi(a.z), bf_hi(b.z), acc);
    acc = fmaf(bf_lo(a.w), bf_lo(b.w), acc);
    acc = fmaf(bf_hi(a.w), bf_hi(b.w), acc);
    return acc;
}

// ---------------------------------------------------------------------------
// Kernel 1 (MFMA, persistent): Wh_bf = bf16(h @ W^T + b); also emits h_bf.
// Grid = 768 blocks (3/CU); each block stages W (bf16, swizzled) into LDS
// ONCE, then grid-strides over 64-node tiles: stage h tile -> MFMA -> store.
// XOR swizzle byte ^= (row&7)<<4 keeps 16-row column reads conflict-free.
// C/D mapping (HW-verified): col = lane&15, row = (lane>>4)*4 + reg.
// ---------------------------------------------------------------------------
__global__ __launch_bounds__(256) void wh_mfma_kernel(
    const float* __restrict__ h, const float* __restrict__ W,
    const float* __restrict__ bias, ushort* __restrict__ Wh_bf,
    ushort* __restrict__ h_bf, int N, int numTiles)
{
    __shared__ alignas(16) unsigned char lds_h[64 * 256];   // [64][128] bf16, swizzled
    __shared__ alignas(16) unsigned char lds_w[128 * 256];  // [128][128] bf16, swizzled

    const int t = threadIdx.x;

    // ---- stage W once: 128 rows x 32 float4 segs --------------------------
#pragma unroll
    for (int it = 0; it < 16; ++it) {
        const int idx = t + 256 * it;           // 0..4095
        const int row = idx >> 5;               // 0..127
        const int seg = idx & 31;
        const float4 x = reinterpret_cast<const float4*>(W)[idx];
        const uint2 p = make_uint2(pack2bf(x.x, x.y), pack2bf(x.z, x.w));
        const int boff = (seg * 8) ^ ((row & 7) << 4);
        *reinterpret_cast<uint2*>(&lds_w[row * 256 + boff]) = p;
    }

    const int lane = t & 63;
    const int wv   = t >> 6;        // 0..3
    const int lr   = lane & 15;     // M/N index within tile
    const int g    = lane >> 4;     // k-group 0..3

    for (int tile = blockIdx.x; tile < numTiles; tile += gridDim.x) {
        const int nodeBase = tile * 64;

        // ---- stage h tile: 64 rows x 32 float4 segs; f32->bf16 ------------
#pragma unroll
        for (int it = 0; it < 8; ++it) {
            const int idx = t + 256 * it;       // 0..2047
            const int row = idx >> 5;           // 0..63
            const int seg = idx & 31;
            const int node = nodeBase + row;
            float4 x = make_float4(0.f, 0.f, 0.f, 0.f);
            if (node < N)
                x = reinterpret_cast<const float4*>(h)[(size_t)node * 32 + seg];
            const uint2 p = make_uint2(pack2bf(x.x, x.y), pack2bf(x.z, x.w));
            const int boff = (seg * 8) ^ ((row & 7) << 4);
            *reinterpret_cast<uint2*>(&lds_h[row * 256 + boff]) = p;
            if (node < N)   // linear global copy for the edge kernel
                *reinterpret_cast<uint2*>(h_bf + (size_t)node * D + seg * 4) = p;
        }
        __syncthreads();    // W (first iter) + h staged

        // A fragments: row = wv*16 + lr
        bf16x8 afrag[4];
        {
            const int row = wv * 16 + lr;
#pragma unroll
            for (int kt = 0; kt < 4; ++kt) {
                const int boff = (kt * 64 + g * 16) ^ ((row & 7) << 4);
                afrag[kt] = *reinterpret_cast<const bf16x8*>(&lds_h[row * 256 + boff]);
            }
        }

#pragma unroll
        for (int ct = 0; ct < 8; ++ct) {
            const int wrow = ct * 16 + lr;      // W row == output col n
            const float bb = bias[wrow];
            f32x4 acc = {bb, bb, bb, bb};
#pragma unroll
            for (int kt = 0; kt < 4; ++kt) {
                const int boff = (kt * 64 + g * 16) ^ ((wrow & 7) << 4);
                const bf16x8 bfrag =
                    *reinterpret_cast<const bf16x8*>(&lds_w[wrow * 256 + boff]);
                acc = __builtin_amdgcn_mfma_f32_16x16x32_bf16(afrag[kt], bfrag, acc, 0, 0, 0);
            }
            const int node0 = nodeBase + wv * 16 + g * 4;
#pragma unroll
            for (int r = 0; r < 4; ++r) {
                if (node0 + r < N)
                    Wh_bf[(size_t)(node0 + r) * D + wrow] = (ushort)f2bf_bits(acc[r]);
            }
        }
        __syncthreads();    // protect lds_h before next tile's staging
    }
}

// ---------------------------------------------------------------------------
// Kernel 2: scores[e] = dot(Wh_bf[src[e],:], h_bf[dst[e],:])
// 8 lanes per edge, 2 edges per group -> 4x uint4 loads in flight per lane
// (8 KB outstanding per wave) to hide gather latency. 3-step shfl_xor
// reduce within the 8-lane group; lane 0 stores a float2 (2 edges).
// ---------------------------------------------------------------------------
__global__ __launch_bounds__(256) void edge_score_kernel(
    const ushort* __restrict__ Wh_bf, const ushort* __restrict__ h_bf,
    const int* __restrict__ src, const int* __restrict__ dst,
    float* __restrict__ out, int E)
{
    const long long t = (long long)blockIdx.x * blockDim.x + threadIdx.x;
    const int grp = (int)(t >> 3);      // edge pair id
    const int l   = (int)(t & 7);
    const int e0  = grp * 2;
    if (e0 >= E) return;
    const int e1 = e0 + 1;
    const bool has1 = e1 < E;

    const int s0 = src[e0], d0 = dst[e0];
    const int s1 = has1 ? src[e1] : s0;
    const int d1 = has1 ? dst[e1] : d0;

    const uint4* A0 = reinterpret_cast<const uint4*>(Wh_bf + (size_t)s0 * D);
    const uint4* B0 = reinterpret_cast<const uint4*>(h_bf  + (size_t)d0 * D);
    const uint4* A1 = reinterpret_cast<const uint4*>(Wh_bf + (size_t)s1 * D);
    const uint4* B1 = reinterpret_cast<const uint4*>(h_bf  + (size_t)d1 * D);

    // 8 loads issued back-to-back: 128 B in flight per lane
    const uint4 a0a = A0[2 * l];
    const uint4 a0b = A0[2 * l + 1];
    const uint4 b0a = B0[2 * l];
    const uint4 b0b = B0[2 * l + 1];
    const uint4 a1a = A1[2 * l];
    const uint4 a1b = A1[2 * l + 1];
    const uint4 b1a = B1[2 * l];
    const uint4 b1b = B1[2 * l + 1];

    float acc0 = dot8(a0a, b0a, 0.f);
    acc0 = dot8(a0b, b0b, acc0);
    float acc1 = dot8(a1a, b1a, 0.f);
    acc1 = dot8(a1b, b1b, acc1);

#pragma unroll
    for (int m = 4; m > 0; m >>= 1) {
        acc0 += __shfl_xor(acc0, m, 64);
        acc1 += __shfl_xor(acc1, m, 64);
    }

    if (l == 0) {
        if (has1)
            *reinterpret_cast<float2*>(out + e0) = make_float2(acc0, acc1);
        else
            out[e0] = acc0;
    }
}

extern "C" void kernel_launch(void* const* d_in, const int* in_sizes, int n_in,
                              void* d_out, int out_size, void* d_ws, size_t ws_size,
                              hipStream_t stream)
{
    const float* h   = (const float*)d_in[0];
    const int*   src = (const int*)  d_in[1];
    const int*   dst = (const int*)  d_in[2];
    const float* W   = (const float*)d_in[3];
    const float* b   = (const float*)d_in[4];
    float* out = (float*)d_out;

    const int N = in_sizes[0] / D;   // 100000
    const int E = in_sizes[1];       // 600000

    ushort* Wh_bf = (ushort*)d_ws;                       // N*D*2 = 25.6 MB
    ushort* h_bf  = (ushort*)d_ws + (size_t)N * D;       // N*D*2 = 25.6 MB

    {
        const int numTiles = (N + 63) / 64;              // 1563
        const int blocks = numTiles < 768 ? numTiles : 768;  // 3 blocks/CU
        wh_mfma_kernel<<<blocks, 256, 0, stream>>>(h, W, b, Wh_bf, h_bf, N, numTiles);
    }
    {
        const long long total = ((long long)E + 1) / 2 * 8;  // 8 lanes per 2 edges
        const int blocks = (int)((total + 255) / 256);
        edge_score_kernel<<<blocks, 256, 0, stream>>>(Wh_bf, h_bf, src, dst, out, E);
    }
}

// Round 7
// 145.176 us; speedup vs baseline: 5.1439x; 1.0222x over previous
//
#include <hip/hip_runtime.h>
#include <hip/hip_bf16.h>

#define D 128

typedef __attribute__((ext_vector_type(8))) short bf16x8;
typedef __attribute__((ext_vector_type(4))) float f32x4;

// ---- bf16 helpers ---------------------------------------------------------
__device__ __forceinline__ unsigned int f2bf_bits(float f) {
    union { float f; unsigned int u; } c; c.f = f;
    return (c.u + 0x7fffu + ((c.u >> 16) & 1u)) >> 16;
}
__device__ __forceinline__ unsigned int pack2bf(float a, float b) {
    union { __hip_bfloat162 h; unsigned int u; } c;
    c.h = __float22bfloat162_rn(make_float2(a, b));
    return c.u;
}
__device__ __forceinline__ float bf_lo(unsigned int u) {
    union { unsigned int u; float f; } c; c.u = u << 16; return c.f;
}
__device__ __forceinline__ float bf_hi(unsigned int u) {
    union { unsigned int u; float f; } c; c.u = u & 0xffff0000u; return c.f;
}

__device__ __forceinline__ float dot8(uint4 a, uint4 b, float acc) {
    acc = fmaf(bf_lo(a.x), bf_lo(b.x), acc);
    acc = fmaf(bf_hi(a.x), bf_hi(b.x), acc);
    acc = fmaf(bf_lo(a.y), bf_lo(b.y), acc);
    acc = fmaf(bf_hi(a.y), bf_hi(b.y), acc);
    acc = fmaf(bf_lo(a.z), bf_lo(b.z), acc);
    acc = fmaf(bf_hi(a.z), bf_hi(b.z), acc);
    acc = fmaf(bf_lo(a.w), bf_lo(b.w), acc);
    acc = fmaf(bf_hi(a.w), bf_hi(b.w), acc);
    return acc;
}

// ---------------------------------------------------------------------------
// Kernel 1 (MFMA, persistent, T14 async-split): Wh_bf = bf16(h @ W^T + b),
// also emits h_bf. Grid = 768 (3/CU). W staged (bf16, swizzled) once per
// block. Grid-stride over 64-node tiles with a software pipeline:
//   prologue: load f32 tile regs
//   loop: convert->LDS + h_bf store | bar | frag read | ISSUE next tile's
//         f32 loads (overlap) | MFMA + Wh stores | bar
// XOR swizzle byte ^= (row&7)<<4 keeps 16-row column reads conflict-free.
// C/D mapping (HW-verified): col = lane&15, row = (lane>>4)*4 + reg.
// ---------------------------------------------------------------------------
__global__ __launch_bounds__(256) void wh_mfma_kernel(
    const float* __restrict__ h, const float* __restrict__ W,
    const float* __restrict__ bias, ushort* __restrict__ Wh_bf,
    ushort* __restrict__ h_bf, int N, int numTiles)
{
    __shared__ alignas(16) unsigned char lds_h[64 * 256];   // [64][128] bf16, swizzled
    __shared__ alignas(16) unsigned char lds_w[128 * 256];  // [128][128] bf16, swizzled

    const int t = threadIdx.x;

    // ---- stage W once: 128 rows x 32 float4 segs --------------------------
#pragma unroll
    for (int it = 0; it < 16; ++it) {
        const int idx = t + 256 * it;           // 0..4095
        const int row = idx >> 5;               // 0..127
        const int seg = idx & 31;
        const float4 x = reinterpret_cast<const float4*>(W)[idx];
        const uint2 p = make_uint2(pack2bf(x.x, x.y), pack2bf(x.z, x.w));
        const int boff = (seg * 8) ^ ((row & 7) << 4);
        *reinterpret_cast<uint2*>(&lds_w[row * 256 + boff]) = p;
    }

    const int lane = t & 63;
    const int wv   = t >> 6;        // 0..3
    const int lr   = lane & 15;     // M/N index within tile
    const int g    = lane >> 4;     // k-group 0..3

    // thread's fixed staging coordinates (same for every tile)
    const int srow[8] = {  (t + 0*256) >> 5, (t + 1*256) >> 5, (t + 2*256) >> 5,
                           (t + 3*256) >> 5, (t + 4*256) >> 5, (t + 5*256) >> 5,
                           (t + 6*256) >> 5, (t + 7*256) >> 5 };
    const int sseg = t & 31;        // seg is (idx&31) = (t&31), invariant in it

    float4 R[8];
    // ---- prologue: load f32 for first tile --------------------------------
    {
        const int tile0 = blockIdx.x;
        const int nodeBase = tile0 * 64;
#pragma unroll
        for (int it = 0; it < 8; ++it) {
            const int node = nodeBase + srow[it];
            R[it] = (node < N)
                ? reinterpret_cast<const float4*>(h)[(size_t)node * 32 + sseg]
                : make_float4(0.f, 0.f, 0.f, 0.f);
        }
    }

    for (int tile = blockIdx.x; tile < numTiles; tile += gridDim.x) {
        const int nodeBase = tile * 64;

        // ---- convert staged regs -> LDS (swizzled) + h_bf global ----------
#pragma unroll
        for (int it = 0; it < 8; ++it) {
            const int row = srow[it];
            const int node = nodeBase + row;
            const float4 x = R[it];
            const uint2 p = make_uint2(pack2bf(x.x, x.y), pack2bf(x.z, x.w));
            const int boff = (sseg * 8) ^ ((row & 7) << 4);
            *reinterpret_cast<uint2*>(&lds_h[row * 256 + boff]) = p;
            if (node < N)
                *reinterpret_cast<uint2*>(h_bf + (size_t)node * D + sseg * 4) = p;
        }
        __syncthreads();    // h tile (and W on first iter) staged

        // ---- A fragments ---------------------------------------------------
        bf16x8 afrag[4];
        {
            const int row = wv * 16 + lr;
#pragma unroll
            for (int kt = 0; kt < 4; ++kt) {
                const int boff = (kt * 64 + g * 16) ^ ((row & 7) << 4);
                afrag[kt] = *reinterpret_cast<const bf16x8*>(&lds_h[row * 256 + boff]);
            }
        }

        // ---- issue next tile's global loads (overlap with MFMA/stores) ----
        const int ntile = tile + gridDim.x;
        if (ntile < numTiles) {
            const int nb = ntile * 64;
#pragma unroll
            for (int it = 0; it < 8; ++it) {
                const int node = nb + srow[it];
                R[it] = (node < N)
                    ? reinterpret_cast<const float4*>(h)[(size_t)node * 32 + sseg]
                    : make_float4(0.f, 0.f, 0.f, 0.f);
            }
        }

        // ---- MFMA + Wh stores ---------------------------------------------
#pragma unroll
        for (int ct = 0; ct < 8; ++ct) {
            const int wrow = ct * 16 + lr;      // W row == output col n
            const float bb = bias[wrow];
            f32x4 acc = {bb, bb, bb, bb};
#pragma unroll
            for (int kt = 0; kt < 4; ++kt) {
                const int boff = (kt * 64 + g * 16) ^ ((wrow & 7) << 4);
                const bf16x8 bfrag =
                    *reinterpret_cast<const bf16x8*>(&lds_w[wrow * 256 + boff]);
                acc = __builtin_amdgcn_mfma_f32_16x16x32_bf16(afrag[kt], bfrag, acc, 0, 0, 0);
            }
            const int node0 = nodeBase + wv * 16 + g * 4;
#pragma unroll
            for (int r = 0; r < 4; ++r) {
                if (node0 + r < N)
                    Wh_bf[(size_t)(node0 + r) * D + wrow] = (ushort)f2bf_bits(acc[r]);
            }
        }
        __syncthreads();    // all waves done with lds_h before next overwrite
    }
}

// ---------------------------------------------------------------------------
// Kernel 2 (unchanged control): scores[e] = dot(Wh_bf[src[e]], h_bf[dst[e]])
// 8 lanes/edge, 2 edges/group; at the L2-miss-path throughput ceiling
// (141 MB @ ~3.3 TB/s, A/B-confirmed rounds 5-6).
// ---------------------------------------------------------------------------
__global__ __launch_bounds__(256) void edge_score_kernel(
    const ushort* __restrict__ Wh_bf, const ushort* __restrict__ h_bf,
    const int* __restrict__ src, const int* __restrict__ dst,
    float* __restrict__ out, int E)
{
    const long long t = (long long)blockIdx.x * blockDim.x + threadIdx.x;
    const int grp = (int)(t >> 3);
    const int l   = (int)(t & 7);
    const int e0  = grp * 2;
    if (e0 >= E) return;
    const int e1 = e0 + 1;
    const bool has1 = e1 < E;

    const int s0 = src[e0], d0 = dst[e0];
    const int s1 = has1 ? src[e1] : s0;
    const int d1 = has1 ? dst[e1] : d0;

    const uint4* A0 = reinterpret_cast<const uint4*>(Wh_bf + (size_t)s0 * D);
    const uint4* B0 = reinterpret_cast<const uint4*>(h_bf  + (size_t)d0 * D);
    const uint4* A1 = reinterpret_cast<const uint4*>(Wh_bf + (size_t)s1 * D);
    const uint4* B1 = reinterpret_cast<const uint4*>(h_bf  + (size_t)d1 * D);

    const uint4 a0a = A0[2 * l];
    const uint4 a0b = A0[2 * l + 1];
    const uint4 b0a = B0[2 * l];
    const uint4 b0b = B0[2 * l + 1];
    const uint4 a1a = A1[2 * l];
    const uint4 a1b = A1[2 * l + 1];
    const uint4 b1a = B1[2 * l];
    const uint4 b1b = B1[2 * l + 1];

    float acc0 = dot8(a0a, b0a, 0.f);
    acc0 = dot8(a0b, b0b, acc0);
    float acc1 = dot8(a1a, b1a, 0.f);
    acc1 = dot8(a1b, b1b, acc1);

#pragma unroll
    for (int m = 4; m > 0; m >>= 1) {
        acc0 += __shfl_xor(acc0, m, 64);
        acc1 += __shfl_xor(acc1, m, 64);
    }

    if (l == 0) {
        if (has1)
            *reinterpret_cast<float2*>(out + e0) = make_float2(acc0, acc1);
        else
            out[e0] = acc0;
    }
}

extern "C" void kernel_launch(void* const* d_in, const int* in_sizes, int n_in,
                              void* d_out, int out_size, void* d_ws, size_t ws_size,
                              hipStream_t stream)
{
    const float* h   = (const float*)d_in[0];
    const int*   src = (const int*)  d_in[1];
    const int*   dst = (const int*)  d_in[2];
    const float* W   = (const float*)d_in[3];
    const float* b   = (const float*)d_in[4];
    float* out = (float*)d_out;

    const int N = in_sizes[0] / D;   // 100000
    const int E = in_sizes[1];       // 600000

    ushort* Wh_bf = (ushort*)d_ws;                       // N*D*2 = 25.6 MB
    ushort* h_bf  = (ushort*)d_ws + (size_t)N * D;       // N*D*2 = 25.6 MB

    {
        const int numTiles = (N + 63) / 64;              // 1563
        const int blocks = numTiles < 768 ? numTiles : 768;  // 3 blocks/CU
        wh_mfma_kernel<<<blocks, 256, 0, stream>>>(h, W, b, Wh_bf, h_bf, N, numTiles);
    }
    {
        const long long total = ((long long)E + 1) / 2 * 8;  // 8 lanes per 2 edges
        const int blocks = (int)((total + 255) / 256);
        edge_score_kernel<<<blocks, 256, 0, stream>>>(Wh_bf, h_bf, src, dst, out, E);
    }
}